// Round 1
// baseline (88.792 us; speedup 1.0000x reference)
//
#include <hip/hip_runtime.h>

// 4-qubit statevector QNN: one thread = one sample, 16-float state in registers.
// Wire w <-> bit mask (8 >> w) of the flattened state index (axis order matches
// the (B,2,2,2,2) reference layout).

template <int MASK>
__device__ __forceinline__ void apply_ry(float st[16], float c, float s) {
#pragma unroll
    for (int i = 0; i < 16; ++i) {
        if (!(i & MASK)) {
            float a0 = st[i];
            float a1 = st[i | MASK];
            st[i]        = fmaf(c, a0, -s * a1);   // c*a0 - s*a1
            st[i | MASK] = fmaf(s, a0,  c * a1);   // s*a0 + c*a1
        }
    }
}

template <int CMASK, int TMASK>
__device__ __forceinline__ void apply_cnot(float st[16]) {
#pragma unroll
    for (int i = 0; i < 16; ++i) {
        if ((i & CMASK) && !(i & TMASK)) {
            float tmp       = st[i];
            st[i]           = st[i | TMASK];
            st[i | TMASK]   = tmp;
        }
    }
}

__global__ __launch_bounds__(256) void qnn_kernel(
    const float* __restrict__ x,      // (B,4)
    const float* __restrict__ qw,     // (3,4)
    const float* __restrict__ W,      // (6,4)
    const float* __restrict__ bias,   // (6,)
    float* __restrict__ out,          // (B,6)
    int B)
{
    __shared__ float wc[12], ws[12];  // cos/sin of weight half-angles
    __shared__ float sW[24], sb[6];

    const int tid = threadIdx.x;
    if (tid < 12) {
        float h = qw[tid] * 0.5f;
        wc[tid] = __cosf(h);
        ws[tid] = __sinf(h);
    }
    if (tid < 24) sW[tid] = W[tid];
    if (tid < 6)  sb[tid] = bias[tid];
    __syncthreads();

    const int b = blockIdx.x * 256 + tid;
    if (b >= B) return;

    const float4 xv = reinterpret_cast<const float4*>(x)[b];

    float st[16];
#pragma unroll
    for (int i = 0; i < 16; ++i) st[i] = 0.0f;
    st[0] = 1.0f;

    // Per-sample RY(x_i) on wire i
    {
        float c, s;
        __sincosf(xv.x * 0.5f, &s, &c); apply_ry<8>(st, c, s);
        __sincosf(xv.y * 0.5f, &s, &c); apply_ry<4>(st, c, s);
        __sincosf(xv.z * 0.5f, &s, &c); apply_ry<2>(st, c, s);
        __sincosf(xv.w * 0.5f, &s, &c); apply_ry<1>(st, c, s);
    }

    // 3 weight layers; CNOT ring after layers 0 and 1
#pragma unroll
    for (int l = 0; l < 3; ++l) {
        apply_ry<8>(st, wc[l * 4 + 0], ws[l * 4 + 0]);
        apply_ry<4>(st, wc[l * 4 + 1], ws[l * 4 + 1]);
        apply_ry<2>(st, wc[l * 4 + 2], ws[l * 4 + 2]);
        apply_ry<1>(st, wc[l * 4 + 3], ws[l * 4 + 3]);
        if (l < 2) {
            apply_cnot<8, 4>(st);   // CNOT(0,1)
            apply_cnot<4, 2>(st);   // CNOT(1,2)
            apply_cnot<2, 1>(st);   // CNOT(2,3)
            apply_cnot<1, 8>(st);   // CNOT(3,0)
        }
    }

    // <Z_w> = sum_i st[i]^2 * (bit_w(i) ? -1 : +1)
    float z[4] = {0.f, 0.f, 0.f, 0.f};
#pragma unroll
    for (int i = 0; i < 16; ++i) {
        float p = st[i] * st[i];
        z[0] += (i & 8) ? -p : p;
        z[1] += (i & 4) ? -p : p;
        z[2] += (i & 2) ? -p : p;
        z[3] += (i & 1) ? -p : p;
    }

    // logits = z @ W^T + b
    float logit[6];
#pragma unroll
    for (int j = 0; j < 6; ++j) {
        float a = sb[j];
        a = fmaf(z[0], sW[j * 4 + 0], a);
        a = fmaf(z[1], sW[j * 4 + 1], a);
        a = fmaf(z[2], sW[j * 4 + 2], a);
        a = fmaf(z[3], sW[j * 4 + 3], a);
        logit[j] = a;
    }

    // softmax over 6
    float m = logit[0];
#pragma unroll
    for (int j = 1; j < 6; ++j) m = fmaxf(m, logit[j]);
    float sum = 0.0f;
#pragma unroll
    for (int j = 0; j < 6; ++j) {
        float e = __expf(logit[j] - m);
        logit[j] = e;
        sum += e;
    }
    const float inv = 1.0f / sum;

    float2* o2 = reinterpret_cast<float2*>(out + (size_t)b * 6);
    o2[0] = make_float2(logit[0] * inv, logit[1] * inv);
    o2[1] = make_float2(logit[2] * inv, logit[3] * inv);
    o2[2] = make_float2(logit[4] * inv, logit[5] * inv);
}

extern "C" void kernel_launch(void* const* d_in, const int* in_sizes, int n_in,
                              void* d_out, int out_size, void* d_ws, size_t ws_size,
                              hipStream_t stream) {
    const float* x    = (const float*)d_in[0];   // (B,4)
    const float* qw   = (const float*)d_in[1];   // (3,4)
    const float* W    = (const float*)d_in[2];   // (6,4)
    const float* bias = (const float*)d_in[3];   // (6,)
    float* out = (float*)d_out;

    const int B = in_sizes[0] / 4;
    const int blocks = (B + 255) / 256;
    qnn_kernel<<<blocks, 256, 0, stream>>>(x, qw, W, bias, out, B);
}

// Round 2
// 85.952 us; speedup vs baseline: 1.0330x; 1.0330x over previous
//
#include <hip/hip_runtime.h>

// 4-qubit statevector QNN: one thread = one sample, 16-float state in registers.
// Wire w <-> bit mask (8 >> w) of the flattened state index.
// Trig via raw v_sin_f32/v_cos_f32 (input in revolutions, sin(2*pi*r)).

#define INV_2PI 0.15915494309189535f

template <int MASK>
__device__ __forceinline__ void apply_ry(float st[16], float c, float s) {
#pragma unroll
    for (int i = 0; i < 16; ++i) {
        if (!(i & MASK)) {
            float a0 = st[i];
            float a1 = st[i | MASK];
            st[i]        = fmaf(c, a0, -s * a1);   // c*a0 - s*a1
            st[i | MASK] = fmaf(s, a0,  c * a1);   // s*a0 + c*a1
        }
    }
}

template <int CMASK, int TMASK>
__device__ __forceinline__ void apply_cnot(float st[16]) {
#pragma unroll
    for (int i = 0; i < 16; ++i) {
        if ((i & CMASK) && !(i & TMASK)) {
            float tmp     = st[i];
            st[i]         = st[i | TMASK];
            st[i | TMASK] = tmp;
        }
    }
}

__global__ __launch_bounds__(256) void qnn_kernel(
    const float* __restrict__ x,      // (B,4)
    const float* __restrict__ qw,     // (3,4)
    const float* __restrict__ W,      // (6,4)
    const float* __restrict__ bias,   // (6,)
    float* __restrict__ out,          // (B,6)
    int B)
{
    __shared__ float wc[12], ws[12];  // cos/sin of weight half-angles
    __shared__ float sW[24], sb[6];

    const int tid = threadIdx.x;
    if (tid < 12) {
        float r = qw[tid] * (0.5f * INV_2PI);     // half-angle in revolutions
        wc[tid] = __builtin_amdgcn_cosf(r);
        ws[tid] = __builtin_amdgcn_sinf(r);
    }
    if (tid < 24) sW[tid] = W[tid];
    if (tid < 6)  sb[tid] = bias[tid];
    __syncthreads();

    const int b = blockIdx.x * 256 + tid;
    if (b >= B) return;

    const float4 xv = reinterpret_cast<const float4*>(x)[b];

    // Initial state = RY(x0..x3)|0000> : pure product state, build by outer product.
    float c0, s0, c1, s1, c2, s2, c3, s3;
    {
        float r0 = xv.x * (0.5f * INV_2PI);
        float r1 = xv.y * (0.5f * INV_2PI);
        float r2 = xv.z * (0.5f * INV_2PI);
        float r3 = xv.w * (0.5f * INV_2PI);
        c0 = __builtin_amdgcn_cosf(r0); s0 = __builtin_amdgcn_sinf(r0);
        c1 = __builtin_amdgcn_cosf(r1); s1 = __builtin_amdgcn_sinf(r1);
        c2 = __builtin_amdgcn_cosf(r2); s2 = __builtin_amdgcn_sinf(r2);
        c3 = __builtin_amdgcn_cosf(r3); s3 = __builtin_amdgcn_sinf(r3);
    }

    float a01[4] = { c0 * c1, c0 * s1, s0 * c1, s0 * s1 };  // wires 0,1 (bits 8,4)
    float a23[4] = { c2 * c3, c2 * s3, s2 * c3, s2 * s3 };  // wires 2,3 (bits 2,1)

    float st[16];
#pragma unroll
    for (int hi = 0; hi < 4; ++hi)
#pragma unroll
        for (int lo = 0; lo < 4; ++lo)
            st[hi * 4 + lo] = a01[hi] * a23[lo];

    // 3 weight layers; CNOT ring after layers 0 and 1
#pragma unroll
    for (int l = 0; l < 3; ++l) {
        apply_ry<8>(st, wc[l * 4 + 0], ws[l * 4 + 0]);
        apply_ry<4>(st, wc[l * 4 + 1], ws[l * 4 + 1]);
        apply_ry<2>(st, wc[l * 4 + 2], ws[l * 4 + 2]);
        apply_ry<1>(st, wc[l * 4 + 3], ws[l * 4 + 3]);
        if (l < 2) {
            apply_cnot<8, 4>(st);   // CNOT(0,1)
            apply_cnot<4, 2>(st);   // CNOT(1,2)
            apply_cnot<2, 1>(st);   // CNOT(2,3)
            apply_cnot<1, 8>(st);   // CNOT(3,0)
        }
    }

    // probs
    float p[16];
#pragma unroll
    for (int i = 0; i < 16; ++i) p[i] = st[i] * st[i];

    // <Z_w> = 1 - 2 * sum_{i: bit_w(i)=1} p[i]
    float z[4];
#pragma unroll
    for (int w = 0; w < 4; ++w) {
        const int m = 8 >> w;
        float sum = 0.0f;
#pragma unroll
        for (int i = 0; i < 16; ++i)
            if (i & m) sum += p[i];
        z[w] = fmaf(-2.0f, sum, 1.0f);
    }

    // logits = z @ W^T + b ; softmax without max-subtraction (|logit| small)
    float e[6];
    float sum = 0.0f;
#pragma unroll
    for (int j = 0; j < 6; ++j) {
        float a = sb[j];
        a = fmaf(z[0], sW[j * 4 + 0], a);
        a = fmaf(z[1], sW[j * 4 + 1], a);
        a = fmaf(z[2], sW[j * 4 + 2], a);
        a = fmaf(z[3], sW[j * 4 + 3], a);
        e[j] = __expf(a);
        sum += e[j];
    }
    const float inv = __builtin_amdgcn_rcpf(sum);

    float2* o2 = reinterpret_cast<float2*>(out + (size_t)b * 6);
    o2[0] = make_float2(e[0] * inv, e[1] * inv);
    o2[1] = make_float2(e[2] * inv, e[3] * inv);
    o2[2] = make_float2(e[4] * inv, e[5] * inv);
}

extern "C" void kernel_launch(void* const* d_in, const int* in_sizes, int n_in,
                              void* d_out, int out_size, void* d_ws, size_t ws_size,
                              hipStream_t stream) {
    const float* x    = (const float*)d_in[0];   // (B,4)
    const float* qw   = (const float*)d_in[1];   // (3,4)
    const float* W    = (const float*)d_in[2];   // (6,4)
    const float* bias = (const float*)d_in[3];   // (6,)
    float* out = (float*)d_out;

    const int B = in_sizes[0] / 4;
    const int blocks = (B + 255) / 256;
    qnn_kernel<<<blocks, 256, 0, stream>>>(x, qw, W, bias, out, B);
}

// Round 3
// 81.898 us; speedup vs baseline: 1.0842x; 1.0495x over previous
//
#include <hip/hip_runtime.h>

// 4-qubit statevector QNN, one thread = one sample.
// Optimizations: layer-0 RY fused into initial angles (same-axis rotations add);
// final RY layer folded into the <Z> extraction (RY on wire w doesn't affect
// z_{w'!=w}); HW trig in revolutions; LDS-staged coalesced float4 output.

#define INV_2PI 0.15915494309189535f

template <int MASK>
__device__ __forceinline__ void apply_ry(float st[16], float c, float s) {
#pragma unroll
    for (int i = 0; i < 16; ++i) {
        if (!(i & MASK)) {
            float a0 = st[i];
            float a1 = st[i | MASK];
            st[i]        = fmaf(c, a0, -s * a1);
            st[i | MASK] = fmaf(s, a0,  c * a1);
        }
    }
}

template <int CMASK, int TMASK>
__device__ __forceinline__ void apply_cnot(float st[16]) {
#pragma unroll
    for (int i = 0; i < 16; ++i) {
        if ((i & CMASK) && !(i & TMASK)) {
            float tmp     = st[i];
            st[i]         = st[i | TMASK];
            st[i | TMASK] = tmp;
        }
    }
}

__global__ __launch_bounds__(256) void qnn_kernel(
    const float* __restrict__ x,      // (B,4)
    const float* __restrict__ qw,     // (3,4)
    const float* __restrict__ W,      // (6,4)
    const float* __restrict__ bias,   // (6,)
    float* __restrict__ out,          // (B,6)
    int B)
{
    __shared__ float qw0[4];           // layer-0 raw angles (fused into x)
    __shared__ float c1h[4], s1h[4];   // layer-1 half-angle cos/sin
    __shared__ float c2f[4], s2f[4];   // layer-2 FULL-angle cos/sin (for fold)
    __shared__ float sW[24], sb[6];
    __shared__ float so[256 * 6];      // output staging

    const int tid = threadIdx.x;
    if (tid < 4) {
        qw0[tid] = qw[tid];
        float r1 = qw[4 + tid] * (0.5f * INV_2PI);
        c1h[tid] = __builtin_amdgcn_cosf(r1);
        s1h[tid] = __builtin_amdgcn_sinf(r1);
        float r2 = qw[8 + tid] * INV_2PI;
        c2f[tid] = __builtin_amdgcn_cosf(r2);
        s2f[tid] = __builtin_amdgcn_sinf(r2);
    }
    if (tid < 24) sW[tid] = W[tid];
    if (tid < 6)  sb[tid] = bias[tid];
    __syncthreads();

    const int b = blockIdx.x * 256 + tid;
    const bool valid = (b < B);

    float4 xv = valid ? reinterpret_cast<const float4*>(x)[b]
                      : make_float4(0.f, 0.f, 0.f, 0.f);

    // Fused initial product state: half-angles (x_k + w0_k)/2
    float c0, s0, c1, s1, c2, s2, c3, s3;
    {
        float r0 = (xv.x + qw0[0]) * (0.5f * INV_2PI);
        float r1 = (xv.y + qw0[1]) * (0.5f * INV_2PI);
        float r2 = (xv.z + qw0[2]) * (0.5f * INV_2PI);
        float r3 = (xv.w + qw0[3]) * (0.5f * INV_2PI);
        c0 = __builtin_amdgcn_cosf(r0); s0 = __builtin_amdgcn_sinf(r0);
        c1 = __builtin_amdgcn_cosf(r1); s1 = __builtin_amdgcn_sinf(r1);
        c2 = __builtin_amdgcn_cosf(r2); s2 = __builtin_amdgcn_sinf(r2);
        c3 = __builtin_amdgcn_cosf(r3); s3 = __builtin_amdgcn_sinf(r3);
    }

    float a01[4] = { c0 * c1, c0 * s1, s0 * c1, s0 * s1 };  // bits 8,4
    float a23[4] = { c2 * c3, c2 * s3, s2 * c3, s2 * s3 };  // bits 2,1

    float st[16];
#pragma unroll
    for (int hi = 0; hi < 4; ++hi)
#pragma unroll
        for (int lo = 0; lo < 4; ++lo)
            st[hi * 4 + lo] = a01[hi] * a23[lo];

    // CNOT ring (register renames), layer-1 RY, CNOT ring
    apply_cnot<8, 4>(st); apply_cnot<4, 2>(st);
    apply_cnot<2, 1>(st); apply_cnot<1, 8>(st);

    apply_ry<8>(st, c1h[0], s1h[0]);
    apply_ry<4>(st, c1h[1], s1h[1]);
    apply_ry<2>(st, c1h[2], s1h[2]);
    apply_ry<1>(st, c1h[3], s1h[3]);

    apply_cnot<8, 4>(st); apply_cnot<4, 2>(st);
    apply_cnot<2, 1>(st); apply_cnot<1, 8>(st);

    // Layer-2 RY folded into <Z_w>:
    // z_w = cos(th_w) * (1 - 2*A1_w) - 2*sin(th_w) * X_w
    float p[16];
#pragma unroll
    for (int i = 0; i < 16; ++i) p[i] = st[i] * st[i];

    float z[4];
#pragma unroll
    for (int w = 0; w < 4; ++w) {
        const int m = 8 >> w;
        float A1 = 0.0f, X = 0.0f;
#pragma unroll
        for (int i = 0; i < 16; ++i) {
            if (!(i & m)) {
                A1 += p[i | m];
                X  = fmaf(st[i], st[i | m], X);
            }
        }
        z[w] = fmaf(c2f[w], fmaf(-2.0f, A1, 1.0f), -2.0f * s2f[w] * X);
    }

    // logits + softmax (no max-subtraction; |logits| small)
    float e[6];
    float sum = 0.0f;
#pragma unroll
    for (int j = 0; j < 6; ++j) {
        float a = sb[j];
        a = fmaf(z[0], sW[j * 4 + 0], a);
        a = fmaf(z[1], sW[j * 4 + 1], a);
        a = fmaf(z[2], sW[j * 4 + 2], a);
        a = fmaf(z[3], sW[j * 4 + 3], a);
        e[j] = __expf(a);
        sum += e[j];
    }
    const float inv = __builtin_amdgcn_rcpf(sum);

    // Stage to LDS, then fully-coalesced float4 stores.
#pragma unroll
    for (int j = 0; j < 6; ++j) so[tid * 6 + j] = e[j] * inv;
    __syncthreads();

    const float4* so4 = reinterpret_cast<const float4*>(so);
    float4* out4 = reinterpret_cast<float4*>(out);
    const long long base = (long long)blockIdx.x * 384;   // 256*6/4
    const long long total4 = (long long)B * 6 / 4;        // B*6 divisible by 4
#pragma unroll
    for (int k = 0; k < 2; ++k) {
        int idx = tid + k * 256;
        if (idx < 384 && base + idx < total4)
            out4[base + idx] = so4[idx];
    }
}

extern "C" void kernel_launch(void* const* d_in, const int* in_sizes, int n_in,
                              void* d_out, int out_size, void* d_ws, size_t ws_size,
                              hipStream_t stream) {
    const float* x    = (const float*)d_in[0];   // (B,4)
    const float* qw   = (const float*)d_in[1];   // (3,4)
    const float* W    = (const float*)d_in[2];   // (6,4)
    const float* bias = (const float*)d_in[3];   // (6,)
    float* out = (float*)d_out;

    const int B = in_sizes[0] / 4;
    const int blocks = (B + 255) / 256;
    qnn_kernel<<<blocks, 256, 0, stream>>>(x, qw, W, bias, out, B);
}